// Round 6
// baseline (136.146 us; speedup 1.0000x reference)
//
#include <hip/hip_runtime.h>

#define N_NODES 100000
#define N_EDGES 1000000
#define HIDDEN 64

// ---- range-pass geometry ----
#define N_RANGES 7
#define C_RANGE 14336                    // 7*14336 = 100352 >= 100000; bins = 57,344 B LDS
#define N_SLICES 73                      // grid = 7*73 = 511 blocks -> 2 blocks/CU everywhere
#define ES 13700                         // even; 73*13700 = 1,000,100 >= 1e6
#define PAIRS_TOTAL (N_EDGES / 2)        // 500,000
#define PPB (ES / 2)                     // 6850 pairs per block
#define A_THREADS 512

// kc[0..3]=(W1@Wout)[k], kc[4]=b1.Wout, kc[5..8]=W1[k][0], kc[9..12]=W1[k][1],
// kc[13]=b1[0], kc[14]=b1[1], kc[15]=Wout[0], kc[16]=Wout[1], kc[17]=bout[0]
__device__ __forceinline__ void compute_consts(
    const float* __restrict__ W1, const float* __restrict__ b1,
    const float* __restrict__ Wout, const float* __restrict__ bout,
    float* kc, int tid) {
    if (tid < 64) {
        float wj = Wout[tid];
        float p0 = W1[0 * HIDDEN + tid] * wj;
        float p1 = W1[1 * HIDDEN + tid] * wj;
        float p2 = W1[2 * HIDDEN + tid] * wj;
        float p3 = W1[3 * HIDDEN + tid] * wj;
        float pb = b1[tid] * wj;
        #pragma unroll
        for (int off = 32; off > 0; off >>= 1) {
            p0 += __shfl_down(p0, off);
            p1 += __shfl_down(p1, off);
            p2 += __shfl_down(p2, off);
            p3 += __shfl_down(p3, off);
            pb += __shfl_down(pb, off);
        }
        if (tid < 4) {
            kc[5 + tid] = W1[tid * HIDDEN + 0];
            kc[9 + tid] = W1[tid * HIDDEN + 1];
        }
        if (tid == 0) {
            kc[0] = p0; kc[1] = p1; kc[2] = p2; kc[3] = p3; kc[4] = pb;
            kc[13] = b1[0]; kc[14] = b1[1];
            kc[15] = Wout[0]; kc[16] = Wout[1];
            kc[17] = bout[0];
        }
    }
}

// contribution of endpoint with features xe toward the OTHER endpoint;
// sgn=+1 for u->v message, -1 for v->u message (sign on the sn*b term).
__device__ __forceinline__ float contrib(
    float4 xe, float cs, float sn_signed,
    float c0, float c1, float c2, float c3, float cb,
    float a0, float a1, float a2, float a3,
    float g0, float g1, float g2, float g3,
    float b10, float b11, float w0, float w1) {
    float h0 = xe.x * a0 + xe.y * a1 + xe.z * a2 + xe.w * a3 + b10;
    float h1 = xe.x * g0 + xe.y * g1 + xe.z * g2 + xe.w * g3 + b11;
    float d  = xe.x * c0 + xe.y * c1 + xe.z * c2 + xe.w * c3 + cb;
    float a  = h0 * w0 + h1 * w1;
    float b  = h0 * w1 - h1 * w0;
    return cs * a + sn_signed * b + (d - a);
}

// ---- Kernel A: block (r,s). Branchless loads (edge pair + phases + 4 x4
// gathers hoisted unconditionally), predicated LDS atomics only.
__global__ __launch_bounds__(A_THREADS) void range_kernel(
    const int2* __restrict__ edges, const float* __restrict__ phases,
    const float4* __restrict__ x4,
    const float* __restrict__ W1, const float* __restrict__ b1,
    const float* __restrict__ Wout, const float* __restrict__ bout,
    float* __restrict__ part) {
    __shared__ float bins[C_RANGE];
    __shared__ float kc[18];
    const int tid = threadIdx.x;
    const int r = blockIdx.x / N_SLICES;
    const int s = blockIdx.x % N_SLICES;

    compute_consts(W1, b1, Wout, bout, kc, tid);
    for (int j = tid; j < C_RANGE; j += A_THREADS) bins[j] = 0.0f;
    __syncthreads();

    const float c0 = kc[0], c1 = kc[1], c2 = kc[2], c3 = kc[3], cb = kc[4];
    const float a0 = kc[5], a1 = kc[6], a2 = kc[7], a3 = kc[8];
    const float g0 = kc[9], g1 = kc[10], g2 = kc[11], g3 = kc[12];
    const float b10 = kc[13], b11 = kc[14], w0 = kc[15], w1 = kc[16];

    const int nlo = r * C_RANGE;
    const int pA = s * PPB;
    const int pB = min(pA + PPB, PAIRS_TOTAL);
    const int4*   __restrict__ epairs = (const int4*)edges;
    const float2* __restrict__ ppairs = (const float2*)phases;

    for (int p = pA + tid; p < pB; p += A_THREADS) {
        // ---- all loads unconditional, single basic block ----
        int4   ee = epairs[p];                 // edge0=(x,y), edge1=(z,w)
        float2 pp = ppairs[p];
        float4 xu0 = x4[ee.x];
        float4 xv0 = x4[ee.y];
        float4 xu1 = x4[ee.z];
        float4 xv1 = x4[ee.w];

        float sn0, cs0, sn1, cs1;
        __sincosf(pp.x, &sn0, &cs0);
        __sincosf(pp.y, &sn1, &cs1);

        float to_v0 = contrib(xu0, cs0,  sn0, c0,c1,c2,c3,cb, a0,a1,a2,a3, g0,g1,g2,g3, b10,b11,w0,w1);
        float to_u0 = contrib(xv0, cs0, -sn0, c0,c1,c2,c3,cb, a0,a1,a2,a3, g0,g1,g2,g3, b10,b11,w0,w1);
        float to_v1 = contrib(xu1, cs1,  sn1, c0,c1,c2,c3,cb, a0,a1,a2,a3, g0,g1,g2,g3, b10,b11,w0,w1);
        float to_u1 = contrib(xv1, cs1, -sn1, c0,c1,c2,c3,cb, a0,a1,a2,a3, g0,g1,g2,g3, b10,b11,w0,w1);

        unsigned ju0 = (unsigned)(ee.x - nlo);
        unsigned jv0 = (unsigned)(ee.y - nlo);
        unsigned ju1 = (unsigned)(ee.z - nlo);
        unsigned jv1 = (unsigned)(ee.w - nlo);
        if (jv0 < C_RANGE) atomicAdd(&bins[jv0], to_v0);
        if (ju0 < C_RANGE) atomicAdd(&bins[ju0], to_u0);
        if (jv1 < C_RANGE) atomicAdd(&bins[jv1], to_v1);
        if (ju1 < C_RANGE) atomicAdd(&bins[ju1], to_u1);
    }
    __syncthreads();

    float* __restrict__ dst = part + (size_t)blockIdx.x * C_RANGE;
    for (int j = tid; j < C_RANGE; j += A_THREADS) dst[j] = bins[j];
}

// ---- Kernel B: out[i] = sum_s part[(r,s)][j] + x_i.(W1@Wout) + b1.Wout + bout
__global__ __launch_bounds__(A_THREADS) void reduce_kernel(
    const float4* __restrict__ x4,
    const float* __restrict__ W1, const float* __restrict__ b1,
    const float* __restrict__ Wout, const float* __restrict__ bout,
    const float* __restrict__ part, float* __restrict__ out) {
    __shared__ float kc[18];
    compute_consts(W1, b1, Wout, bout, kc, threadIdx.x);
    __syncthreads();
    int i = blockIdx.x * A_THREADS + threadIdx.x;
    if (i >= N_NODES) return;
    int r = i / C_RANGE;
    int j = i - r * C_RANGE;
    const float* __restrict__ p = part + ((size_t)r * N_SLICES) * C_RANGE + j;
    float sum = 0.0f;
    #pragma unroll 8
    for (int s = 0; s < N_SLICES; s++) sum += p[(size_t)s * C_RANGE];
    float4 xi = x4[i];
    out[i] = sum + xi.x * kc[0] + xi.y * kc[1] + xi.z * kc[2] + xi.w * kc[3]
           + kc[4] + kc[17];
}

// ---- Fallback (ws too small): direct device atomics ----------------------
__global__ void precompute_kernel(const float* __restrict__ W1,
                                  const float* __restrict__ b1,
                                  const float* __restrict__ Wout,
                                  const float* __restrict__ bout,
                                  float* __restrict__ consts) {
    __shared__ float kc[18];
    compute_consts(W1, b1, Wout, bout, kc, threadIdx.x);
    __syncthreads();
    if (threadIdx.x < 18) consts[threadIdx.x] = kc[threadIdx.x];
}

__global__ void edge_atomic_kernel(const int2* __restrict__ edges,
                                   const float* __restrict__ phases,
                                   const float4* __restrict__ x4,
                                   const float* __restrict__ consts,
                                   float* __restrict__ rep) {
    int e = blockIdx.x * blockDim.x + threadIdx.x;
    if (e >= N_EDGES) return;
    float c0 = consts[0], c1 = consts[1], c2 = consts[2], c3 = consts[3];
    float cb = consts[4];
    float a0 = consts[5], a1 = consts[6], a2 = consts[7], a3 = consts[8];
    float g0 = consts[9], g1 = consts[10], g2 = consts[11], g3 = consts[12];
    float b10 = consts[13], b11 = consts[14], w0 = consts[15], w1 = consts[16];
    int2 ed = edges[e];
    float ph = phases[e];
    float sn, cs;
    __sincosf(ph, &sn, &cs);
    float4 xu = x4[ed.x];
    float4 xv = x4[ed.y];
    atomicAdd(rep + ed.y, contrib(xu, cs,  sn, c0,c1,c2,c3,cb, a0,a1,a2,a3, g0,g1,g2,g3, b10,b11,w0,w1));
    atomicAdd(rep + ed.x, contrib(xv, cs, -sn, c0,c1,c2,c3,cb, a0,a1,a2,a3, g0,g1,g2,g3, b10,b11,w0,w1));
}

__global__ void final_kernel(const float4* __restrict__ x4,
                             const float* __restrict__ consts,
                             const float* __restrict__ rep,
                             float* __restrict__ out) {
    int i = blockIdx.x * blockDim.x + threadIdx.x;
    if (i >= N_NODES) return;
    float4 xi = x4[i];
    out[i] = rep[i] + xi.x * consts[0] + xi.y * consts[1] + xi.z * consts[2]
           + xi.w * consts[3] + consts[4] + consts[17];
}

extern "C" void kernel_launch(void* const* d_in, const int* in_sizes, int n_in,
                              void* d_out, int out_size, void* d_ws, size_t ws_size,
                              hipStream_t stream) {
    const float* x      = (const float*)d_in[0];
    const int*   edges  = (const int*)d_in[1];
    const float* W1     = (const float*)d_in[2];
    const float* b1     = (const float*)d_in[3];
    const float* phases = (const float*)d_in[4];
    const float* Wout   = (const float*)d_in[5];
    const float* bout   = (const float*)d_in[6];
    float* out = (float*)d_out;

    const size_t part_bytes =
        (size_t)N_RANGES * N_SLICES * C_RANGE * sizeof(float);   // ~29.3 MB

    if (ws_size >= part_bytes) {
        float* part = (float*)d_ws;
        // No memset needed: every part slot is written by exactly one block.
        range_kernel<<<N_RANGES * N_SLICES, A_THREADS, 0, stream>>>(
            (const int2*)edges, phases, (const float4*)x,
            W1, b1, Wout, bout, part);
        reduce_kernel<<<(N_NODES + A_THREADS - 1) / A_THREADS, A_THREADS, 0, stream>>>(
            (const float4*)x, W1, b1, Wout, bout, part, out);
    } else {
        float* consts = (float*)d_ws;
        float* rep    = (float*)((char*)d_ws + 256);
        hipMemsetAsync(rep, 0, N_NODES * sizeof(float), stream);
        precompute_kernel<<<1, 64, 0, stream>>>(W1, b1, Wout, bout, consts);
        edge_atomic_kernel<<<(N_EDGES + 255) / 256, 256, 0, stream>>>(
            (const int2*)edges, phases, (const float4*)x, consts, rep);
        final_kernel<<<(N_NODES + 255) / 256, 256, 0, stream>>>(
            (const float4*)x, consts, rep, out);
    }
}

// Round 7
// 111.680 us; speedup vs baseline: 1.2191x; 1.2191x over previous
//
#include <hip/hip_runtime.h>

#define N_NODES 100000
#define N_EDGES 1000000
#define HIDDEN 64

// ---- range-pass geometry ----
#define N_RANGES 8
#define C_RANGE 13312                    // 8*13312 = 106496 >= 100000; bins = 53,248 B
#define N_SLICES 64                      // grid = 8*64 = 512 blocks = exactly 2/CU
#define ES (N_EDGES / N_SLICES)          // 15625 edges per slice (exact)
#define CH 2048                          // edges per chunk
#define NC ((ES + CH - 1) / CH)          // 8 chunks (7*2048 + 1289)
#define QCAP 704                         // queue cap: mean <=545, sigma ~22 -> +7 sigma
#define A_THREADS 512

// kc[0..3]=(W1@Wout)[k], kc[4]=b1.Wout, kc[5..8]=W1[k][0], kc[9..12]=W1[k][1],
// kc[13]=b1[0], kc[14]=b1[1], kc[15]=Wout[0], kc[16]=Wout[1], kc[17]=bout[0]
__device__ __forceinline__ void compute_consts(
    const float* __restrict__ W1, const float* __restrict__ b1,
    const float* __restrict__ Wout, const float* __restrict__ bout,
    float* kc, int tid) {
    if (tid < 64) {
        float wj = Wout[tid];
        float p0 = W1[0 * HIDDEN + tid] * wj;
        float p1 = W1[1 * HIDDEN + tid] * wj;
        float p2 = W1[2 * HIDDEN + tid] * wj;
        float p3 = W1[3 * HIDDEN + tid] * wj;
        float pb = b1[tid] * wj;
        #pragma unroll
        for (int off = 32; off > 0; off >>= 1) {
            p0 += __shfl_down(p0, off);
            p1 += __shfl_down(p1, off);
            p2 += __shfl_down(p2, off);
            p3 += __shfl_down(p3, off);
            pb += __shfl_down(pb, off);
        }
        if (tid < 4) {
            kc[5 + tid] = W1[tid * HIDDEN + 0];
            kc[9 + tid] = W1[tid * HIDDEN + 1];
        }
        if (tid == 0) {
            kc[0] = p0; kc[1] = p1; kc[2] = p2; kc[3] = p3; kc[4] = pb;
            kc[13] = b1[0]; kc[14] = b1[1];
            kc[15] = Wout[0]; kc[16] = Wout[1];
            kc[17] = bout[0];
        }
    }
}

__device__ __forceinline__ float contrib(
    float4 xe, float cs, float sn_signed,
    float c0, float c1, float c2, float c3, float cb,
    float a0, float a1, float a2, float a3,
    float g0, float g1, float g2, float g3,
    float b10, float b11, float w0, float w1) {
    float h0 = xe.x * a0 + xe.y * a1 + xe.z * a2 + xe.w * a3 + b10;
    float h1 = xe.x * g0 + xe.y * g1 + xe.z * g2 + xe.w * g3 + b11;
    float d  = xe.x * c0 + xe.y * c1 + xe.z * c2 + xe.w * c3 + cb;
    float a  = h0 * w0 + h1 * w1;
    float b  = h0 * w1 - h1 * w0;
    return cs * a + sn_signed * b + (d - a);
}

// ---- Kernel A: scan->compact->dense-gather pipeline, double-buffered ------
__global__ __launch_bounds__(A_THREADS) void range_kernel(
    const int2* __restrict__ edges, const float* __restrict__ phases,
    const float4* __restrict__ x4,
    const float* __restrict__ W1, const float* __restrict__ b1,
    const float* __restrict__ Wout, const float* __restrict__ bout,
    float* __restrict__ part) {
    __shared__ float bins[C_RANGE];         // 53,248 B
    __shared__ uint2 qbuf[2][QCAP];         // 11,264 B
    __shared__ int   qcnt[2];
    __shared__ int   qn_sh[2];
    __shared__ float kc[18];
    const int tid = threadIdx.x;
    const int r = blockIdx.x >> 6;          // range
    const int s = blockIdx.x & 63;          // edge slice

    compute_consts(W1, b1, Wout, bout, kc, tid);
    for (int j = tid; j < C_RANGE; j += A_THREADS) bins[j] = 0.0f;
    if (tid < 2) { qcnt[tid] = 0; qn_sh[tid] = 0; }
    __syncthreads();

    const float c0 = kc[0], c1 = kc[1], c2 = kc[2], c3 = kc[3], cb = kc[4];
    const float a0 = kc[5], a1 = kc[6], a2 = kc[7], a3 = kc[8];
    const float g0 = kc[9], g1 = kc[10], g2 = kc[11], g3 = kc[12];
    const float b10 = kc[13], b11 = kc[14], w0 = kc[15], w1 = kc[16];

    const int nlo = r * C_RANGE;
    const int e0 = s * ES;

    // scan chunk cc, push packed in-range contributions into qbuf[dstb]
    auto scan_push = [&](int cc, int dstb) {
        const int ebase = e0 + cc * CH;
        const int eend  = min(ebase + CH, e0 + ES);
        for (int e = ebase + tid; e < eend; e += A_THREADS) {
            int2 ed = edges[e];
            float ph = phases[e];
            unsigned jv = (unsigned)(ed.y - nlo);
            unsigned ju = (unsigned)(ed.x - nlo);
            if (jv < C_RANGE) {             // msg u->v lands on v; src = u; +sn
                int pos = atomicAdd(&qcnt[dstb], 1);
                if (pos < QCAP)
                    qbuf[dstb][pos] = make_uint2(jv | ((unsigned)ed.x << 15),
                                                 __float_as_uint(ph));
            }
            if (ju < C_RANGE) {             // msg v->u lands on u; src = v; -sn
                int pos = atomicAdd(&qcnt[dstb], 1);
                if (pos < QCAP)
                    qbuf[dstb][pos] = make_uint2(ju | 0x4000u | ((unsigned)ed.y << 15),
                                                 __float_as_uint(ph));
            }
        }
    };

    // prologue: fill buffer 0
    scan_push(0, 0);
    __syncthreads();
    if (tid == 0) { qn_sh[0] = min(qcnt[0], QCAP); qcnt[0] = 0; }
    __syncthreads();

    for (int c = 0; c < NC; c++) {
        const int curb = c & 1, pb = curb ^ 1;
        if (c + 1 < NC) scan_push(c + 1, pb);       // overlap next scan...
        const int qn = qn_sh[curb];
        for (int q = tid; q < qn; q += A_THREADS) { // ...with dense gathers
            uint2 it = qbuf[curb][q];
            unsigned pk = it.x;
            int dest = pk & 0x3FFFu;
            float sg = (pk & 0x4000u) ? -1.0f : 1.0f;
            int src = pk >> 15;
            float ph = __uint_as_float(it.y);
            float sn, cs;
            __sincosf(ph, &sn, &cs);
            float4 xs = x4[src];
            float val = contrib(xs, cs, sg * sn, c0, c1, c2, c3, cb,
                                a0, a1, a2, a3, g0, g1, g2, g3, b10, b11, w0, w1);
            atomicAdd(&bins[dest], val);
        }
        __syncthreads();
        if (tid == 0) { qn_sh[pb] = min(qcnt[pb], QCAP); qcnt[pb] = 0; }
        __syncthreads();
    }

    float* __restrict__ dst = part + (size_t)blockIdx.x * C_RANGE;
    for (int j = tid; j < C_RANGE; j += A_THREADS) dst[j] = bins[j];
}

// ---- Kernel B: out[i] = sum_s part[(r,s)][j] + x_i.(W1@Wout) + b1.Wout + bout
__global__ __launch_bounds__(A_THREADS) void reduce_kernel(
    const float4* __restrict__ x4,
    const float* __restrict__ W1, const float* __restrict__ b1,
    const float* __restrict__ Wout, const float* __restrict__ bout,
    const float* __restrict__ part, float* __restrict__ out) {
    __shared__ float kc[18];
    compute_consts(W1, b1, Wout, bout, kc, threadIdx.x);
    __syncthreads();
    int i = blockIdx.x * A_THREADS + threadIdx.x;
    if (i >= N_NODES) return;
    int r = i / C_RANGE;
    int j = i - r * C_RANGE;
    const float* __restrict__ p = part + ((size_t)r * N_SLICES) * C_RANGE + j;
    float sum = 0.0f;
    #pragma unroll 16
    for (int s = 0; s < N_SLICES; s++) sum += p[(size_t)s * C_RANGE];
    float4 xi = x4[i];
    out[i] = sum + xi.x * kc[0] + xi.y * kc[1] + xi.z * kc[2] + xi.w * kc[3]
           + kc[4] + kc[17];
}

// ---- Fallback (ws too small): direct device atomics ----------------------
__global__ void precompute_kernel(const float* __restrict__ W1,
                                  const float* __restrict__ b1,
                                  const float* __restrict__ Wout,
                                  const float* __restrict__ bout,
                                  float* __restrict__ consts) {
    __shared__ float kc[18];
    compute_consts(W1, b1, Wout, bout, kc, threadIdx.x);
    __syncthreads();
    if (threadIdx.x < 18) consts[threadIdx.x] = kc[threadIdx.x];
}

__global__ void edge_atomic_kernel(const int2* __restrict__ edges,
                                   const float* __restrict__ phases,
                                   const float4* __restrict__ x4,
                                   const float* __restrict__ consts,
                                   float* __restrict__ rep) {
    int e = blockIdx.x * blockDim.x + threadIdx.x;
    if (e >= N_EDGES) return;
    float c0 = consts[0], c1 = consts[1], c2 = consts[2], c3 = consts[3];
    float cb = consts[4];
    float a0 = consts[5], a1 = consts[6], a2 = consts[7], a3 = consts[8];
    float g0 = consts[9], g1 = consts[10], g2 = consts[11], g3 = consts[12];
    float b10 = consts[13], b11 = consts[14], w0 = consts[15], w1 = consts[16];
    int2 ed = edges[e];
    float ph = phases[e];
    float sn, cs;
    __sincosf(ph, &sn, &cs);
    float4 xu = x4[ed.x];
    float4 xv = x4[ed.y];
    atomicAdd(rep + ed.y, contrib(xu, cs,  sn, c0,c1,c2,c3,cb, a0,a1,a2,a3, g0,g1,g2,g3, b10,b11,w0,w1));
    atomicAdd(rep + ed.x, contrib(xv, cs, -sn, c0,c1,c2,c3,cb, a0,a1,a2,a3, g0,g1,g2,g3, b10,b11,w0,w1));
}

__global__ void final_kernel(const float4* __restrict__ x4,
                             const float* __restrict__ consts,
                             const float* __restrict__ rep,
                             float* __restrict__ out) {
    int i = blockIdx.x * blockDim.x + threadIdx.x;
    if (i >= N_NODES) return;
    float4 xi = x4[i];
    out[i] = rep[i] + xi.x * consts[0] + xi.y * consts[1] + xi.z * consts[2]
           + xi.w * consts[3] + consts[4] + consts[17];
}

extern "C" void kernel_launch(void* const* d_in, const int* in_sizes, int n_in,
                              void* d_out, int out_size, void* d_ws, size_t ws_size,
                              hipStream_t stream) {
    const float* x      = (const float*)d_in[0];
    const int*   edges  = (const int*)d_in[1];
    const float* W1     = (const float*)d_in[2];
    const float* b1     = (const float*)d_in[3];
    const float* phases = (const float*)d_in[4];
    const float* Wout   = (const float*)d_in[5];
    const float* bout   = (const float*)d_in[6];
    float* out = (float*)d_out;

    const size_t part_bytes =
        (size_t)N_RANGES * N_SLICES * C_RANGE * sizeof(float);   // ~13.6 MB

    if (ws_size >= part_bytes) {
        float* part = (float*)d_ws;
        // No memset needed: every part slot is written by exactly one block.
        range_kernel<<<N_RANGES * N_SLICES, A_THREADS, 0, stream>>>(
            (const int2*)edges, phases, (const float4*)x,
            W1, b1, Wout, bout, part);
        reduce_kernel<<<(N_NODES + A_THREADS - 1) / A_THREADS, A_THREADS, 0, stream>>>(
            (const float4*)x, W1, b1, Wout, bout, part, out);
    } else {
        float* consts = (float*)d_ws;
        float* rep    = (float*)((char*)d_ws + 256);
        hipMemsetAsync(rep, 0, N_NODES * sizeof(float), stream);
        precompute_kernel<<<1, 64, 0, stream>>>(W1, b1, Wout, bout, consts);
        edge_atomic_kernel<<<(N_EDGES + 255) / 256, 256, 0, stream>>>(
            (const int2*)edges, phases, (const float4*)x, consts, rep);
        final_kernel<<<(N_NODES + 255) / 256, 256, 0, stream>>>(
            (const float4*)x, consts, rep, out);
    }
}

// Round 8
// 103.464 us; speedup vs baseline: 1.3159x; 1.0794x over previous
//
#include <hip/hip_runtime.h>

#define N_NODES 100000
#define N_EDGES 1000000
#define HIDDEN 64

// ---- range-pass geometry ----
#define N_RANGES 7
#define C_RANGE 14336                    // 7*14336 = 100352 >= 100000; bins = 57,344 B
#define N_SLICES 73                      // 7*73 = 511 blocks -> 2 blocks/CU (57.4 KB LDS)
#define ES 13700                         // even; 73*13700 = 1,000,100 >= 1e6
#define PAIRS_TOTAL (N_EDGES / 2)        // 500,000
#define PPB (ES / 2)                     // 6850 pairs per block
#define A_THREADS 512

// kc[0..3]=(W1@Wout)[k], kc[4]=b1.Wout, kc[5..8]=W1[k][0], kc[9..12]=W1[k][1],
// kc[13]=b1[0], kc[14]=b1[1], kc[15]=Wout[0], kc[16]=Wout[1], kc[17]=bout[0]
__device__ __forceinline__ void compute_consts(
    const float* __restrict__ W1, const float* __restrict__ b1,
    const float* __restrict__ Wout, const float* __restrict__ bout,
    float* kc, int tid) {
    if (tid < 64) {
        float wj = Wout[tid];
        float p0 = W1[0 * HIDDEN + tid] * wj;
        float p1 = W1[1 * HIDDEN + tid] * wj;
        float p2 = W1[2 * HIDDEN + tid] * wj;
        float p3 = W1[3 * HIDDEN + tid] * wj;
        float pb = b1[tid] * wj;
        #pragma unroll
        for (int off = 32; off > 0; off >>= 1) {
            p0 += __shfl_down(p0, off);
            p1 += __shfl_down(p1, off);
            p2 += __shfl_down(p2, off);
            p3 += __shfl_down(p3, off);
            pb += __shfl_down(pb, off);
        }
        if (tid < 4) {
            kc[5 + tid] = W1[tid * HIDDEN + 0];
            kc[9 + tid] = W1[tid * HIDDEN + 1];
        }
        if (tid == 0) {
            kc[0] = p0; kc[1] = p1; kc[2] = p2; kc[3] = p3; kc[4] = pb;
            kc[13] = b1[0]; kc[14] = b1[1];
            kc[15] = Wout[0]; kc[16] = Wout[1];
            kc[17] = bout[0];
        }
    }
}

__device__ __forceinline__ float contrib(
    float4 xe, float cs, float sn_signed,
    float c0, float c1, float c2, float c3, float cb,
    float a0, float a1, float a2, float a3,
    float g0, float g1, float g2, float g3,
    float b10, float b11, float w0, float w1) {
    float h0 = xe.x * a0 + xe.y * a1 + xe.z * a2 + xe.w * a3 + b10;
    float h1 = xe.x * g0 + xe.y * g1 + xe.z * g2 + xe.w * g3 + b11;
    float d  = xe.x * c0 + xe.y * c1 + xe.z * c2 + xe.w * c3 + cb;
    float a  = h0 * w0 + h1 * w1;
    float b  = h0 * w1 - h1 * w0;
    return cs * a + sn_signed * b + (d - a);
}

// ---- Kernel A: block (r,s). Single basic-block inner loop: paired edge
// loads, ADDRESS-CLAMPED unconditional gathers (inactive lanes broadcast-read
// node 0 => ~1 extra cache line per wave), unconditional sincos+FMA,
// predicated LDS atomics only. 2 barriers total.
__global__ __launch_bounds__(A_THREADS) void range_kernel(
    const int2* __restrict__ edges, const float* __restrict__ phases,
    const float4* __restrict__ x4,
    const float* __restrict__ W1, const float* __restrict__ b1,
    const float* __restrict__ Wout, const float* __restrict__ bout,
    float* __restrict__ part) {
    __shared__ float bins[C_RANGE];         // 57,344 B
    __shared__ float kc[18];
    const int tid = threadIdx.x;
    const int r = blockIdx.x / N_SLICES;
    const int s = blockIdx.x % N_SLICES;

    compute_consts(W1, b1, Wout, bout, kc, tid);
    {   // vectorized zero: C_RANGE/4 = 3584 float4 slots
        float4 z = make_float4(0.f, 0.f, 0.f, 0.f);
        float4* b4 = (float4*)bins;
        for (int j = tid; j < C_RANGE / 4; j += A_THREADS) b4[j] = z;
    }
    __syncthreads();

    const float c0 = kc[0], c1 = kc[1], c2 = kc[2], c3 = kc[3], cb = kc[4];
    const float a0 = kc[5], a1 = kc[6], a2 = kc[7], a3 = kc[8];
    const float g0 = kc[9], g1 = kc[10], g2 = kc[11], g3 = kc[12];
    const float b10 = kc[13], b11 = kc[14], w0 = kc[15], w1 = kc[16];

    const int nlo = r * C_RANGE;
    const int pA = s * PPB;
    const int pB = min(pA + PPB, PAIRS_TOTAL);
    const int4*   __restrict__ epairs = (const int4*)edges;
    const float2* __restrict__ ppairs = (const float2*)phases;

    #pragma unroll 2
    for (int p = pA + tid; p < pB; p += A_THREADS) {
        int4   ee = epairs[p];                 // edge0=(x,y), edge1=(z,w)
        float2 pp = ppairs[p];

        unsigned jv0 = (unsigned)(ee.y - nlo); // dest v0, src u0
        unsigned ju0 = (unsigned)(ee.x - nlo); // dest u0, src v0
        unsigned jv1 = (unsigned)(ee.w - nlo);
        unsigned ju1 = (unsigned)(ee.z - nlo);
        bool pv0 = jv0 < C_RANGE, pu0 = ju0 < C_RANGE;
        bool pv1 = jv1 < C_RANGE, pu1 = ju1 < C_RANGE;

        // clamped gathers — always issued, single basic block
        float4 xsv0 = x4[pv0 ? ee.x : 0];
        float4 xsu0 = x4[pu0 ? ee.y : 0];
        float4 xsv1 = x4[pv1 ? ee.z : 0];
        float4 xsu1 = x4[pu1 ? ee.w : 0];

        float sn0, cs0, sn1, cs1;
        __sincosf(pp.x, &sn0, &cs0);
        __sincosf(pp.y, &sn1, &cs1);

        float tv0 = contrib(xsv0, cs0,  sn0, c0,c1,c2,c3,cb, a0,a1,a2,a3, g0,g1,g2,g3, b10,b11,w0,w1);
        float tu0 = contrib(xsu0, cs0, -sn0, c0,c1,c2,c3,cb, a0,a1,a2,a3, g0,g1,g2,g3, b10,b11,w0,w1);
        float tv1 = contrib(xsv1, cs1,  sn1, c0,c1,c2,c3,cb, a0,a1,a2,a3, g0,g1,g2,g3, b10,b11,w0,w1);
        float tu1 = contrib(xsu1, cs1, -sn1, c0,c1,c2,c3,cb, a0,a1,a2,a3, g0,g1,g2,g3, b10,b11,w0,w1);

        if (pv0) atomicAdd(&bins[jv0], tv0);
        if (pu0) atomicAdd(&bins[ju0], tu0);
        if (pv1) atomicAdd(&bins[jv1], tv1);
        if (pu1) atomicAdd(&bins[ju1], tu1);
    }
    __syncthreads();

    // vectorized flush
    float4* __restrict__ d4 = (float4*)(part + (size_t)blockIdx.x * C_RANGE);
    const float4* b4 = (const float4*)bins;
    for (int j = tid; j < C_RANGE / 4; j += A_THREADS) d4[j] = b4[j];
}

// ---- Kernel B: out[i] = sum_s part[(r,s)][j] + x_i.(W1@Wout) + b1.Wout + bout
__global__ __launch_bounds__(A_THREADS) void reduce_kernel(
    const float4* __restrict__ x4,
    const float* __restrict__ W1, const float* __restrict__ b1,
    const float* __restrict__ Wout, const float* __restrict__ bout,
    const float* __restrict__ part, float* __restrict__ out) {
    __shared__ float kc[18];
    compute_consts(W1, b1, Wout, bout, kc, threadIdx.x);
    __syncthreads();
    int i = blockIdx.x * A_THREADS + threadIdx.x;
    if (i >= N_NODES) return;
    int r = i / C_RANGE;
    int j = i - r * C_RANGE;
    const float* __restrict__ p = part + ((size_t)r * N_SLICES) * C_RANGE + j;
    float sum = 0.0f;
    #pragma unroll 8
    for (int s = 0; s < N_SLICES; s++) sum += p[(size_t)s * C_RANGE];
    float4 xi = x4[i];
    out[i] = sum + xi.x * kc[0] + xi.y * kc[1] + xi.z * kc[2] + xi.w * kc[3]
           + kc[4] + kc[17];
}

// ---- Fallback (ws too small): direct device atomics ----------------------
__global__ void precompute_kernel(const float* __restrict__ W1,
                                  const float* __restrict__ b1,
                                  const float* __restrict__ Wout,
                                  const float* __restrict__ bout,
                                  float* __restrict__ consts) {
    __shared__ float kc[18];
    compute_consts(W1, b1, Wout, bout, kc, threadIdx.x);
    __syncthreads();
    if (threadIdx.x < 18) consts[threadIdx.x] = kc[threadIdx.x];
}

__global__ void edge_atomic_kernel(const int2* __restrict__ edges,
                                   const float* __restrict__ phases,
                                   const float4* __restrict__ x4,
                                   const float* __restrict__ consts,
                                   float* __restrict__ rep) {
    int e = blockIdx.x * blockDim.x + threadIdx.x;
    if (e >= N_EDGES) return;
    float c0 = consts[0], c1 = consts[1], c2 = consts[2], c3 = consts[3];
    float cb = consts[4];
    float a0 = consts[5], a1 = consts[6], a2 = consts[7], a3 = consts[8];
    float g0 = consts[9], g1 = consts[10], g2 = consts[11], g3 = consts[12];
    float b10 = consts[13], b11 = consts[14], w0 = consts[15], w1 = consts[16];
    int2 ed = edges[e];
    float ph = phases[e];
    float sn, cs;
    __sincosf(ph, &sn, &cs);
    float4 xu = x4[ed.x];
    float4 xv = x4[ed.y];
    atomicAdd(rep + ed.y, contrib(xu, cs,  sn, c0,c1,c2,c3,cb, a0,a1,a2,a3, g0,g1,g2,g3, b10,b11,w0,w1));
    atomicAdd(rep + ed.x, contrib(xv, cs, -sn, c0,c1,c2,c3,cb, a0,a1,a2,a3, g0,g1,g2,g3, b10,b11,w0,w1));
}

__global__ void final_kernel(const float4* __restrict__ x4,
                             const float* __restrict__ consts,
                             const float* __restrict__ rep,
                             float* __restrict__ out) {
    int i = blockIdx.x * blockDim.x + threadIdx.x;
    if (i >= N_NODES) return;
    float4 xi = x4[i];
    out[i] = rep[i] + xi.x * consts[0] + xi.y * consts[1] + xi.z * consts[2]
           + xi.w * consts[3] + consts[4] + consts[17];
}

extern "C" void kernel_launch(void* const* d_in, const int* in_sizes, int n_in,
                              void* d_out, int out_size, void* d_ws, size_t ws_size,
                              hipStream_t stream) {
    const float* x      = (const float*)d_in[0];
    const int*   edges  = (const int*)d_in[1];
    const float* W1     = (const float*)d_in[2];
    const float* b1     = (const float*)d_in[3];
    const float* phases = (const float*)d_in[4];
    const float* Wout   = (const float*)d_in[5];
    const float* bout   = (const float*)d_in[6];
    float* out = (float*)d_out;

    const size_t part_bytes =
        (size_t)N_RANGES * N_SLICES * C_RANGE * sizeof(float);   // ~29.3 MB

    if (ws_size >= part_bytes) {
        float* part = (float*)d_ws;
        // No memset needed: every part slot is written by exactly one block.
        range_kernel<<<N_RANGES * N_SLICES, A_THREADS, 0, stream>>>(
            (const int2*)edges, phases, (const float4*)x,
            W1, b1, Wout, bout, part);
        reduce_kernel<<<(N_NODES + A_THREADS - 1) / A_THREADS, A_THREADS, 0, stream>>>(
            (const float4*)x, W1, b1, Wout, bout, part, out);
    } else {
        float* consts = (float*)d_ws;
        float* rep    = (float*)((char*)d_ws + 256);
        hipMemsetAsync(rep, 0, N_NODES * sizeof(float), stream);
        precompute_kernel<<<1, 64, 0, stream>>>(W1, b1, Wout, bout, consts);
        edge_atomic_kernel<<<(N_EDGES + 255) / 256, 256, 0, stream>>>(
            (const int2*)edges, phases, (const float4*)x, consts, rep);
        final_kernel<<<(N_NODES + 255) / 256, 256, 0, stream>>>(
            (const float4*)x, consts, rep, out);
    }
}